// Round 2
// baseline (246.859 us; speedup 1.0000x reference)
//
#include <hip/hip_runtime.h>
#include <math.h>

#define BDIM 4
#define LDIM 512
#define EDIM 1024
#define HDIM 128
#define TILE 31            // interior y-tile per block (s-grid is 32x32 with 1 halo)
#define NT   17            // 17*31 = 527 >= 512 tiles per spatial dim

// x is the product of two post-ReLU values => x >= 0, but formula is valid for all x.
// tanh(x) = 1 - 2/(exp(2x)+1); exp(2x) = exp2(x * 2/ln2)
__device__ __forceinline__ float fast_tanh(float x) {
  float e = __builtin_amdgcn_exp2f(x * 2.885390081777927f);
  return 1.0f - 2.0f * __builtin_amdgcn_rcpf(e + 1.0f);
}

// ---------------------------------------------------------------------------
// Kernel 1: hid[row][h] = relu( emb[row] @ W1 + b1 ),  rows 0..2047 = rec,
// rows 2048..4095 = lig. Block: 16 rows x 128 cols, 256 threads
// (thread = 4 rows x 2 cols). A-tile staged in LDS (broadcast reads), W1 from
// global (coalesced, L2-resident: 512 KB).
// ---------------------------------------------------------------------------
__global__ __launch_bounds__(256) void gemm_relu(
    const float* __restrict__ rec, const float* __restrict__ lig,
    const float* __restrict__ W1, const float* __restrict__ b1,
    float* __restrict__ hid) {
  __shared__ float a_lds[16][64];
  const int t = threadIdx.x;
  const int r0 = blockIdx.x * 16;
  const int c = t & 63;          // col, plus c+64
  const int g = t >> 6;          // row group 0..3 -> rows g*4..g*4+3
  float acc[4][2];
#pragma unroll
  for (int u = 0; u < 4; ++u) acc[u][0] = acc[u][1] = 0.f;

  // staging assignment: one float4 per thread per K-chunk
  const int lrow = t >> 4;          // 0..15
  const int lk = (t & 15) * 4;      // 0..60
  const int grow = r0 + lrow;
  const float* src = (grow < BDIM * LDIM ? rec + (size_t)grow * EDIM
                                         : lig + (size_t)(grow - BDIM * LDIM) * EDIM) + lk;

  for (int k0 = 0; k0 < EDIM; k0 += 64) {
    float4 v = *(const float4*)(src + k0);
    __syncthreads();               // previous chunk's reads done before overwrite
    *(float4*)&a_lds[lrow][lk] = v;
    __syncthreads();
    const float* wp = W1 + (size_t)k0 * HDIM + c;
#pragma unroll 8
    for (int k = 0; k < 64; k += 4) {
      float w0a = wp[(k + 0) * HDIM];
      float w1a = wp[(k + 1) * HDIM];
      float w2a = wp[(k + 2) * HDIM];
      float w3a = wp[(k + 3) * HDIM];
      float w0b = wp[(k + 0) * HDIM + 64];
      float w1b = wp[(k + 1) * HDIM + 64];
      float w2b = wp[(k + 2) * HDIM + 64];
      float w3b = wp[(k + 3) * HDIM + 64];
#pragma unroll
      for (int u = 0; u < 4; ++u) {
        float4 a = *(const float4*)&a_lds[g * 4 + u][k];  // wave-broadcast read
        acc[u][0] = fmaf(a.x, w0a, fmaf(a.y, w1a, fmaf(a.z, w2a, fmaf(a.w, w3a, acc[u][0]))));
        acc[u][1] = fmaf(a.x, w0b, fmaf(a.y, w1b, fmaf(a.z, w2b, fmaf(a.w, w3b, acc[u][1]))));
      }
    }
  }
  const float b0 = b1[c], b64 = b1[c + 64];
#pragma unroll
  for (int u = 0; u < 4; ++u) {
    int gr = r0 + g * 4 + u;
    hid[(size_t)gr * HDIM + c]      = fmaxf(acc[u][0] + b0, 0.f);
    hid[(size_t)gr * HDIM + c + 64] = fmaxf(acc[u][1] + b64, 0.f);
  }
}

// ---------------------------------------------------------------------------
// Kernel 2: per 31x31 y-tile, compute s_k(p,q) = sum_h tanh(r_p*l_q)*w_k on a
// 32x32 grid (1-halo), assemble y, reduce max -> partial[block].
// ---------------------------------------------------------------------------
__global__ __launch_bounds__(256) void bilinear_max(
    const float* __restrict__ hid, const float4* __restrict__ cw4,
    const float* __restrict__ cb, float* __restrict__ partial) {
  __shared__ float rl[32][132];     // +4 pad: row stride 528B -> conflict-free b128
  __shared__ float ll[32][132];
  __shared__ float4 wl[HDIM];       // {w00,w01,w10,w11} per h
  __shared__ float4 sl[32][33];     // s taps per (p,q)
  __shared__ float wred[4];

  const int t = threadIdx.x;
  const int b = blockIdx.z;
  const int ib = (int)blockIdx.y * TILE - 1;   // s row ii -> i = ib + ii
  const int jb = (int)blockIdx.x * TILE - 1;

  if (t < HDIM) wl[t] = cw4[t];
  const float4 z4 = make_float4(0.f, 0.f, 0.f, 0.f);
  for (int p = t; p < 1024; p += 256) {        // 32 rows x 32 float4
    int row = p >> 5, q4 = (p & 31) * 4;
    int i = ib + row;
    float4 v = z4;
    if (i >= 0 && i < LDIM) v = *(const float4*)(hid + ((size_t)(b * LDIM + i)) * HDIM + q4);
    *(float4*)&rl[row][q4] = v;
    int j = jb + row;
    float4 u = z4;
    if (j >= 0 && j < LDIM) u = *(const float4*)(hid + ((size_t)((BDIM + b) * LDIM + j)) * HDIM + q4);
    *(float4*)&ll[row][q4] = u;
  }
  __syncthreads();

  // phase B: each thread: one ii row, 4 jj columns (jlo, jlo+8, +16, +24)
  const int ii = t >> 3;
  const int jlo = t & 7;
  float4 acc0 = z4, acc1 = z4, acc2 = z4, acc3 = z4;
  for (int h = 0; h < HDIM; h += 4) {
    float4 r4 = *(const float4*)&rl[ii][h];
    float4 w0 = wl[h], w1 = wl[h + 1], w2 = wl[h + 2], w3 = wl[h + 3];
#define DO_JJ(ACC, JJ)                                                        \
    {                                                                         \
      float4 l4 = *(const float4*)&ll[(JJ)][h];                               \
      float t0 = fast_tanh(r4.x * l4.x);                                      \
      float t1 = fast_tanh(r4.y * l4.y);                                      \
      float t2 = fast_tanh(r4.z * l4.z);                                      \
      float t3 = fast_tanh(r4.w * l4.w);                                      \
      ACC.x = fmaf(t0, w0.x, fmaf(t1, w1.x, fmaf(t2, w2.x, fmaf(t3, w3.x, ACC.x)))); \
      ACC.y = fmaf(t0, w0.y, fmaf(t1, w1.y, fmaf(t2, w2.y, fmaf(t3, w3.y, ACC.y)))); \
      ACC.z = fmaf(t0, w0.z, fmaf(t1, w1.z, fmaf(t2, w2.z, fmaf(t3, w3.z, ACC.z)))); \
      ACC.w = fmaf(t0, w0.w, fmaf(t1, w1.w, fmaf(t2, w2.w, fmaf(t3, w3.w, ACC.w)))); \
    }
    DO_JJ(acc0, jlo)
    DO_JJ(acc1, jlo + 8)
    DO_JJ(acc2, jlo + 16)
    DO_JJ(acc3, jlo + 24)
#undef DO_JJ
  }
  sl[ii][jlo]      = acc0;
  sl[ii][jlo + 8]  = acc1;
  sl[ii][jlo + 16] = acc2;
  sl[ii][jlo + 24] = acc3;
  __syncthreads();

  // phase C: y[i,j] = cb + s00(i-1,j-1)+s01(i-1,j)+s10(i,j-1)+s11(i,j); max
  float m = -INFINITY;
  const float cbv = cb[0];
  for (int p = t; p < 1024; p += 256) {
    int jj = p & 31, iy = p >> 5;
    int i = ib + iy, j = jb + jj;
    if (iy > 0 && jj > 0 && i < LDIM && j < LDIM) {
      float v = cbv + sl[iy - 1][jj - 1].x + sl[iy - 1][jj].y
                    + sl[iy][jj - 1].z + sl[iy][jj].w;
      m = fmaxf(m, v);
    }
  }
#pragma unroll
  for (int off = 32; off > 0; off >>= 1) m = fmaxf(m, __shfl_down(m, off, 64));
  if ((t & 63) == 0) wred[t >> 6] = m;
  __syncthreads();
  if (t == 0) {
    float mm = fmaxf(fmaxf(wred[0], wred[1]), fmaxf(wred[2], wred[3]));
    partial[((size_t)b * NT + blockIdx.y) * NT + blockIdx.x] = mm;
  }
}

// ---------------------------------------------------------------------------
// Kernel 3: reduce 17x17 partials per batch, sigmoid, write 4 outputs.
// ---------------------------------------------------------------------------
__global__ __launch_bounds__(64) void finalize(const float* __restrict__ partial,
                                               float* __restrict__ out) {
  const int b = blockIdx.x, t = threadIdx.x;
  float m = -INFINITY;
  for (int p = t; p < NT * NT; p += 64) m = fmaxf(m, partial[b * NT * NT + p]);
#pragma unroll
  for (int off = 32; off > 0; off >>= 1) m = fmaxf(m, __shfl_down(m, off, 64));
  if (t == 0) out[b] = 1.f / (1.f + expf(-m));
}

extern "C" void kernel_launch(void* const* d_in, const int* in_sizes, int n_in,
                              void* d_out, int out_size, void* d_ws, size_t ws_size,
                              hipStream_t stream) {
  const float* rec = (const float*)d_in[0];
  const float* lig = (const float*)d_in[1];
  const float* W1  = (const float*)d_in[2];
  const float* b1  = (const float*)d_in[3];
  const float* cw  = (const float*)d_in[4];   // (1,H,2,2) = float4 per h
  const float* cb  = (const float*)d_in[5];
  float* out = (float*)d_out;

  float* hid     = (float*)d_ws;                          // 4096*128 f32 = 2 MB
  float* partial = hid + (size_t)2 * BDIM * LDIM * HDIM;  // 4*289 f32

  gemm_relu<<<dim3(2 * BDIM * LDIM / 16), 256, 0, stream>>>(rec, lig, W1, b1, hid);
  bilinear_max<<<dim3(NT, NT, BDIM), 256, 0, stream>>>(hid, (const float4*)cw, cb, partial);
  finalize<<<dim3(BDIM), 64, 0, stream>>>(partial, out);
}

// Round 3
// 156.016 us; speedup vs baseline: 1.5823x; 1.5823x over previous
//
#include <hip/hip_runtime.h>
#include <math.h>

#define BDIM 4
#define LDIM 512
#define EDIM 1024
#define HDIM 128
#define TILE 31            // interior y-tile per block (s-grid is 32x32 with 1 halo)
#define NT   17            // 17*31 = 527 >= 512 tiles per spatial dim
#define K2   2.885390081777927f   // 2/ln(2): tanh(x) = 1 - 2/(exp2(K2*x)+1)

typedef const __attribute__((address_space(1))) void* gptr_t;
typedef __attribute__((address_space(3))) void* lptr_t;

__device__ __forceinline__ void load_lds16(const void* g, void* l) {
  __builtin_amdgcn_global_load_lds((gptr_t)g, (lptr_t)l, 16, 0, 0);
}

// tanh from pre-scaled argument x2 = K2 * x, valid for x >= 0 (true here: x is a
// product of two post-ReLU values). exp2 overflow -> inf -> rcp -> 0 -> tanh=1. OK.
__device__ __forceinline__ float tanh_pre(float x2) {
  float e = __builtin_amdgcn_exp2f(x2);
  return fmaf(-2.0f, __builtin_amdgcn_rcpf(e + 1.0f), 1.0f);
}

// ---------------------------------------------------------------------------
// Kernel 1: hid[row][h] = relu( emb[row] @ W1 + b1 ). rows 0..2047 = rec,
// 2048..4095 = lig. 256 blocks x 256 threads; block = 16 rows x 128 cols;
// thread = 2 rows x 4 cols (8 acc). K-chunks of 32 double-buffered in LDS via
// global_load_lds(16B): W1 tile 32x128 (4 rounds), A tile 16x32 (1 round,
// waves 0-1). One barrier per chunk: next chunk's async loads overlap this
// chunk's FMAs; the barrier's vmcnt drain completes them.
// ---------------------------------------------------------------------------
__global__ __launch_bounds__(256) void gemm_relu(
    const float* __restrict__ rec, const float* __restrict__ lig,
    const float* __restrict__ W1, const float* __restrict__ b1,
    float* __restrict__ hid) {
  __shared__ float w_lds[2][32 * 128];   // 16 KB each
  __shared__ float a_lds[2][16 * 32];    // 2 KB each
  const int t = threadIdx.x;
  const int r0 = (int)blockIdx.x * 16;   // 0..4080
  const float* abase = (r0 < BDIM * LDIM)
                           ? rec + (size_t)r0 * EDIM
                           : lig + (size_t)(r0 - BDIM * LDIM) * EDIM;

  const int rg = t >> 5;            // 0..7 -> rows 2rg, 2rg+1
  const int c4 = (t & 31) * 4;      // cols c4..c4+3
  float acc[2][4];
#pragma unroll
  for (int r = 0; r < 2; ++r)
#pragma unroll
    for (int j = 0; j < 4; ++j) acc[r][j] = 0.f;

#define STAGE(BUF, K0)                                                         \
  {                                                                            \
    _Pragma("unroll")                                                          \
    for (int rnd = 0; rnd < 4; ++rnd)                                          \
      load_lds16(W1 + (size_t)(K0)*HDIM + rnd * 1024 + t * 4,                  \
                 &w_lds[BUF][rnd * 1024 + t * 4]);                             \
    if (t < 128)                                                               \
      load_lds16(abase + (size_t)(t >> 3) * EDIM + (K0) + (t & 7) * 4,         \
                 &a_lds[BUF][t * 4]);                                          \
  }

  STAGE(0, 0)
  __syncthreads();                       // barrier drains vmcnt -> chunk 0 ready
  for (int k0 = 0; k0 < EDIM; k0 += 32) {
    const int buf = (k0 >> 5) & 1;
    if (k0 + 32 < EDIM) STAGE(buf ^ 1, k0 + 32)   // async, lands during compute
#pragma unroll
    for (int kk = 0; kk < 32; kk += 4) {
      float4 a0 = *(const float4*)&a_lds[buf][(2 * rg)     * 32 + kk];
      float4 a1 = *(const float4*)&a_lds[buf][(2 * rg + 1) * 32 + kk];
      float4 w0 = *(const float4*)&w_lds[buf][(kk + 0) * 128 + c4];
      float4 w1 = *(const float4*)&w_lds[buf][(kk + 1) * 128 + c4];
      float4 w2 = *(const float4*)&w_lds[buf][(kk + 2) * 128 + c4];
      float4 w3 = *(const float4*)&w_lds[buf][(kk + 3) * 128 + c4];
      acc[0][0] = fmaf(a0.x, w0.x, fmaf(a0.y, w1.x, fmaf(a0.z, w2.x, fmaf(a0.w, w3.x, acc[0][0]))));
      acc[0][1] = fmaf(a0.x, w0.y, fmaf(a0.y, w1.y, fmaf(a0.z, w2.y, fmaf(a0.w, w3.y, acc[0][1]))));
      acc[0][2] = fmaf(a0.x, w0.z, fmaf(a0.y, w1.z, fmaf(a0.z, w2.z, fmaf(a0.w, w3.z, acc[0][2]))));
      acc[0][3] = fmaf(a0.x, w0.w, fmaf(a0.y, w1.w, fmaf(a0.z, w2.w, fmaf(a0.w, w3.w, acc[0][3]))));
      acc[1][0] = fmaf(a1.x, w0.x, fmaf(a1.y, w1.x, fmaf(a1.z, w2.x, fmaf(a1.w, w3.x, acc[1][0]))));
      acc[1][1] = fmaf(a1.x, w0.y, fmaf(a1.y, w1.y, fmaf(a1.z, w2.y, fmaf(a1.w, w3.y, acc[1][1]))));
      acc[1][2] = fmaf(a1.x, w0.z, fmaf(a1.y, w1.z, fmaf(a1.z, w2.z, fmaf(a1.w, w3.z, acc[1][2]))));
      acc[1][3] = fmaf(a1.x, w0.w, fmaf(a1.y, w1.w, fmaf(a1.z, w2.w, fmaf(a1.w, w3.w, acc[1][3]))));
    }
    __syncthreads();   // waves done with buf; next chunk's loads drained
  }
#undef STAGE

  const float4 bias = *(const float4*)&b1[c4];
#pragma unroll
  for (int r = 0; r < 2; ++r) {
    float4 o;
    o.x = fmaxf(acc[r][0] + bias.x, 0.f);
    o.y = fmaxf(acc[r][1] + bias.y, 0.f);
    o.z = fmaxf(acc[r][2] + bias.z, 0.f);
    o.w = fmaxf(acc[r][3] + bias.w, 0.f);
    *(float4*)&hid[(size_t)(r0 + 2 * rg + r) * HDIM + c4] = o;
  }
}

// ---------------------------------------------------------------------------
// Kernel 2: per 31x31 y-tile, compute s_k(p,q) = sum_h tanh(r_p*l_q)*w_k on a
// 32x32 grid (1-halo), assemble y, reduce max -> partial[block].
// r-tile is pre-scaled by K2 at staging so tanh needs no per-element scale mul.
// ---------------------------------------------------------------------------
__global__ __launch_bounds__(256) void bilinear_max(
    const float* __restrict__ hid, const float4* __restrict__ cw4,
    const float* __restrict__ cb, float* __restrict__ partial) {
  __shared__ float rl[32][132];     // +4 pad: row stride 528B -> conflict-free b128
  __shared__ float ll[32][132];
  __shared__ float4 wl[HDIM];       // {w00,w01,w10,w11} per h
  __shared__ float4 sl[32][33];     // s taps per (p,q)
  __shared__ float wred[4];

  const int t = threadIdx.x;
  const int b = blockIdx.z;
  const int ib = (int)blockIdx.y * TILE - 1;   // s row ii -> i = ib + ii
  const int jb = (int)blockIdx.x * TILE - 1;

  if (t < HDIM) wl[t] = cw4[t];
  const float4 z4 = make_float4(0.f, 0.f, 0.f, 0.f);
  for (int p = t; p < 1024; p += 256) {        // 32 rows x 32 float4
    int row = p >> 5, q4 = (p & 31) * 4;
    int i = ib + row;
    float4 v = z4;
    if (i >= 0 && i < LDIM) {
      v = *(const float4*)(hid + ((size_t)(b * LDIM + i)) * HDIM + q4);
      v.x *= K2; v.y *= K2; v.z *= K2; v.w *= K2;   // pre-scale r side
    }
    *(float4*)&rl[row][q4] = v;
    int j = jb + row;
    float4 u = z4;
    if (j >= 0 && j < LDIM) u = *(const float4*)(hid + ((size_t)((BDIM + b) * LDIM + j)) * HDIM + q4);
    *(float4*)&ll[row][q4] = u;
  }
  __syncthreads();

  // phase B: each thread: one ii row, 4 jj columns (jlo, jlo+8, +16, +24)
  const int ii = t >> 3;
  const int jlo = t & 7;
  float4 acc0 = z4, acc1 = z4, acc2 = z4, acc3 = z4;
#pragma unroll 2
  for (int h = 0; h < HDIM; h += 4) {
    float4 r4 = *(const float4*)&rl[ii][h];
    float4 w0 = wl[h], w1 = wl[h + 1], w2 = wl[h + 2], w3 = wl[h + 3];
#define DO_JJ(ACC, JJ)                                                        \
    {                                                                         \
      float4 l4 = *(const float4*)&ll[(JJ)][h];                               \
      float t0 = tanh_pre(r4.x * l4.x);                                       \
      float t1 = tanh_pre(r4.y * l4.y);                                       \
      float t2 = tanh_pre(r4.z * l4.z);                                       \
      float t3 = tanh_pre(r4.w * l4.w);                                       \
      ACC.x = fmaf(t0, w0.x, fmaf(t1, w1.x, fmaf(t2, w2.x, fmaf(t3, w3.x, ACC.x)))); \
      ACC.y = fmaf(t0, w0.y, fmaf(t1, w1.y, fmaf(t2, w2.y, fmaf(t3, w3.y, ACC.y)))); \
      ACC.z = fmaf(t0, w0.z, fmaf(t1, w1.z, fmaf(t2, w2.z, fmaf(t3, w3.z, ACC.z)))); \
      ACC.w = fmaf(t0, w0.w, fmaf(t1, w1.w, fmaf(t2, w2.w, fmaf(t3, w3.w, ACC.w)))); \
    }
    DO_JJ(acc0, jlo)
    DO_JJ(acc1, jlo + 8)
    DO_JJ(acc2, jlo + 16)
    DO_JJ(acc3, jlo + 24)
#undef DO_JJ
  }
  sl[ii][jlo]      = acc0;
  sl[ii][jlo + 8]  = acc1;
  sl[ii][jlo + 16] = acc2;
  sl[ii][jlo + 24] = acc3;
  __syncthreads();

  // phase C: y[i,j] = cb + s00(i-1,j-1)+s01(i-1,j)+s10(i,j-1)+s11(i,j); max
  float m = -INFINITY;
  const float cbv = cb[0];
  for (int p = t; p < 1024; p += 256) {
    int jj = p & 31, iy = p >> 5;
    int i = ib + iy, j = jb + jj;
    if (iy > 0 && jj > 0 && i < LDIM && j < LDIM) {
      float v = cbv + sl[iy - 1][jj - 1].x + sl[iy - 1][jj].y
                    + sl[iy][jj - 1].z + sl[iy][jj].w;
      m = fmaxf(m, v);
    }
  }
#pragma unroll
  for (int off = 32; off > 0; off >>= 1) m = fmaxf(m, __shfl_down(m, off, 64));
  if ((t & 63) == 0) wred[t >> 6] = m;
  __syncthreads();
  if (t == 0) {
    float mm = fmaxf(fmaxf(wred[0], wred[1]), fmaxf(wred[2], wred[3]));
    partial[((size_t)b * NT + blockIdx.y) * NT + blockIdx.x] = mm;
  }
}

// ---------------------------------------------------------------------------
// Kernel 3: reduce 17x17 partials per batch, sigmoid, write 4 outputs.
// ---------------------------------------------------------------------------
__global__ __launch_bounds__(64) void finalize(const float* __restrict__ partial,
                                               float* __restrict__ out) {
  const int b = blockIdx.x, t = threadIdx.x;
  float m = -INFINITY;
  for (int p = t; p < NT * NT; p += 64) m = fmaxf(m, partial[b * NT * NT + p]);
#pragma unroll
  for (int off = 32; off > 0; off >>= 1) m = fmaxf(m, __shfl_down(m, off, 64));
  if (t == 0) out[b] = 1.f / (1.f + expf(-m));
}

extern "C" void kernel_launch(void* const* d_in, const int* in_sizes, int n_in,
                              void* d_out, int out_size, void* d_ws, size_t ws_size,
                              hipStream_t stream) {
  const float* rec = (const float*)d_in[0];
  const float* lig = (const float*)d_in[1];
  const float* W1  = (const float*)d_in[2];
  const float* b1  = (const float*)d_in[3];
  const float* cw  = (const float*)d_in[4];   // (1,H,2,2) = float4 per h
  const float* cb  = (const float*)d_in[5];
  float* out = (float*)d_out;

  float* hid     = (float*)d_ws;                          // 4096*128 f32 = 2 MB
  float* partial = hid + (size_t)2 * BDIM * LDIM * HDIM;  // 4*289 f32

  gemm_relu<<<dim3(2 * BDIM * LDIM / 16), 256, 0, stream>>>(rec, lig, W1, b1, hid);
  bilinear_max<<<dim3(NT, NT, BDIM), 256, 0, stream>>>(hid, (const float4*)cw, cb, partial);
  finalize<<<dim3(BDIM), 64, 0, stream>>>(partial, out);
}

// Round 4
// 143.226 us; speedup vs baseline: 1.7236x; 1.0893x over previous
//
#include <hip/hip_runtime.h>
#include <hip/hip_fp16.h>
#include <math.h>

#define BDIM 4
#define LDIM 512
#define EDIM 1024
#define HDIM 128
#define TILE 31            // interior y-tile per block (s-grid is 32x32 with 1 halo)
#define NT   17            // 17*31 = 527 >= 512 tiles per spatial dim
#define K2   2.885390081777927f   // 2/ln(2): tanh(x) = 1 - 2/(exp2(K2*x)+1)

typedef unsigned short ushort_t;
typedef __attribute__((ext_vector_type(8))) _Float16 half8;
typedef __attribute__((ext_vector_type(4))) float f32x4;

struct __align__(16) H8 { __half2 p[4]; };
struct __align__(8)  H4 { __half2 a, b; };

// tanh from pre-scaled argument x2 = K2*x, x >= 0 here (product of post-ReLU
// values; rec side pre-scaled by K2 in gemm epilogue). exp2 inf -> rcp 0 -> 1. OK.
__device__ __forceinline__ float tanh_pre(float x2) {
  float e = __builtin_amdgcn_exp2f(x2);
  return fmaf(-2.0f, __builtin_amdgcn_rcpf(e + 1.0f), 1.0f);
}

// ---------------------------------------------------------------------------
// Kernel 0: W1 (1024x128 f32, k-major) -> Wt (128x1024 f16, n-major).
// 16384 threads, one 8-half output vector each; reads coalesced per j.
// ---------------------------------------------------------------------------
__global__ __launch_bounds__(256) void wcvt(const float* __restrict__ W1,
                                            ushort_t* __restrict__ Wt) {
  const int g = (int)blockIdx.x * 256 + threadIdx.x;  // 0..16383
  const int n = g & 127, k8 = g >> 7;                 // k8: 0..127
  float v[8];
#pragma unroll
  for (int j = 0; j < 8; ++j) v[j] = W1[(size_t)(k8 * 8 + j) * HDIM + n];
  H8 o;
#pragma unroll
  for (int j = 0; j < 4; ++j) o.p[j] = __floats2half2_rn(v[2 * j], v[2 * j + 1]);
  *(H8*)&Wt[(size_t)n * EDIM + k8 * 8] = o;
}

// ---------------------------------------------------------------------------
// Kernel 1: hid[row][h] = relu(emb[row] @ W1 + b1) via f16 MFMA 16x16x32.
// 256 blocks x 16 rows (full H=128 cols). 4 waves; wave w owns cols
// [32w,32w+32) = 2 N-tiles of 16. K-chunk 32 = one MFMA depth, double-buffered.
// A staged f32->f16 in VGPRs; W from pre-converted Wt ([n][k], k-contiguous).
// LDS rows padded to 40 halves (80 B) -> 2-way max (free) on frag reads.
// Output f16; rec rows pre-scaled by K2 for the tanh kernel.
// ---------------------------------------------------------------------------
__global__ __launch_bounds__(256) void gemm_f16(
    const float* __restrict__ rec, const float* __restrict__ lig,
    const ushort_t* __restrict__ Wt, const float* __restrict__ b1,
    ushort_t* __restrict__ hid) {
  __shared__ ushort_t Wlds[2][128 * 40];   // 10 KB each
  __shared__ ushort_t Alds[2][16 * 40];    // 1.25 KB each
  const int t = threadIdx.x;
  const int r0 = (int)blockIdx.x * 16;
  const float* abase = (r0 < BDIM * LDIM)
                           ? rec + (size_t)r0 * EDIM
                           : lig + (size_t)(r0 - BDIM * LDIM) * EDIM;
  const int l = t & 63, wv = t >> 6;
  const int kg = (l >> 4) * 8;                       // A/B frag k-group
  const int aoff = (l & 15) * 40 + kg;               // A[m][k], m=lane&15
  const int boff0 = (32 * wv + (l & 15)) * 40 + kg;  // B[n][k], n=lane&15
  const int boff1 = boff0 + 16 * 40;
  const int wn = t >> 1, wk = (t & 1) * 16;          // W staging: 2 b128/thread
  const int am = t >> 3, ak = (t & 7) * 4;           // A staging (t<128)

  f32x4 acc0 = {0.f, 0.f, 0.f, 0.f}, acc1 = {0.f, 0.f, 0.f, 0.f};

#define STAGE(BUF, K0)                                                        \
  {                                                                           \
    const ushort_t* wsrc = Wt + (size_t)wn * EDIM + (K0) + wk;                \
    H8 w0 = *(const H8*)wsrc;                                                 \
    H8 w1 = *(const H8*)(wsrc + 8);                                           \
    *(H8*)&Wlds[BUF][wn * 40 + wk] = w0;                                      \
    *(H8*)&Wlds[BUF][wn * 40 + wk + 8] = w1;                                  \
    if (t < 128) {                                                            \
      float4 av = *(const float4*)(abase + (size_t)am * EDIM + (K0) + ak);    \
      H4 ah;                                                                  \
      ah.a = __floats2half2_rn(av.x, av.y);                                   \
      ah.b = __floats2half2_rn(av.z, av.w);                                   \
      *(H4*)&Alds[BUF][am * 40 + ak] = ah;                                    \
    }                                                                         \
  }

  STAGE(0, 0)
  __syncthreads();
  for (int c = 0; c < 32; ++c) {
    const int buf = c & 1;
    if (c < 31) STAGE(buf ^ 1, (c + 1) * 32)   // lands while MFMA runs
    half8 av  = *(const half8*)&Alds[buf][aoff];
    half8 bv0 = *(const half8*)&Wlds[buf][boff0];
    half8 bv1 = *(const half8*)&Wlds[buf][boff1];
    acc0 = __builtin_amdgcn_mfma_f32_16x16x32_f16(av, bv0, acc0, 0, 0, 0);
    acc1 = __builtin_amdgcn_mfma_f32_16x16x32_f16(av, bv1, acc1, 0, 0, 0);
    __syncthreads();
  }
#undef STAGE

  // C/D: col = lane&15, row = (lane>>4)*4 + reg  [m89-verified]
  const float scale = (r0 < BDIM * LDIM) ? K2 : 1.0f;
  const int rbase = r0 + ((l >> 4) << 2);
  const int col0 = (wv << 5) + (l & 15);
#pragma unroll
  for (int nt = 0; nt < 2; ++nt) {
    const int col = col0 + nt * 16;
    const float bias = b1[col];
    f32x4 a = nt ? acc1 : acc0;
#pragma unroll
    for (int r = 0; r < 4; ++r) {
      float v = fmaxf(a[r] + bias, 0.f) * scale;
      ((_Float16*)hid)[(size_t)(rbase + r) * HDIM + col] = (_Float16)v;
    }
  }
}

// ---------------------------------------------------------------------------
// Kernel 2: per 31x31 y-tile, s_k(p,q) = sum_h tanh(r_p*l_q)*w_k on a 32x32
// grid (1-halo), assemble y, reduce max -> partial[block]. f16 tiles (36.4 KB
// LDS -> 4 blocks/CU); packed f16 products, f32 tanh+accumulate.
// ---------------------------------------------------------------------------
__global__ __launch_bounds__(256, 4) void bilinear_max(
    const ushort_t* __restrict__ hid, const float4* __restrict__ cw4,
    const float* __restrict__ cb, float* __restrict__ partial) {
  __shared__ ushort_t rl[32][136];   // +8 pad: 272 B row stride
  __shared__ ushort_t ll[32][136];
  __shared__ float4 wl[HDIM];        // {w00,w01,w10,w11} per h
  __shared__ float4 sl[32][33];      // s taps per (p,q)
  __shared__ float wred[4];

  const int t = threadIdx.x;
  const int b = blockIdx.z;
  const int ib = (int)blockIdx.y * TILE - 1;
  const int jb = (int)blockIdx.x * TILE - 1;

  if (t < HDIM) wl[t] = cw4[t];
  H8 z;
  z.p[0] = z.p[1] = z.p[2] = z.p[3] = __floats2half2_rn(0.f, 0.f);
  for (int p = t; p < 1024; p += 256) {   // 64 rows x 16 b128 segments
    int r = p >> 4, seg = (p & 15) * 8;
    if (r < 32) {
      int i = ib + r;
      H8 v = z;
      if (i >= 0 && i < LDIM) v = *(const H8*)&hid[((size_t)(b * LDIM + i)) * HDIM + seg];
      *(H8*)&rl[r][seg] = v;
    } else {
      int j = jb + (r - 32);
      H8 v = z;
      if (j >= 0 && j < LDIM) v = *(const H8*)&hid[((size_t)((BDIM + b) * LDIM + j)) * HDIM + seg];
      *(H8*)&ll[r - 32][seg] = v;
    }
  }
  __syncthreads();

  // phase B: thread = one ii row x 4 jj cols (jlo, +8, +16, +24)
  const int ii = t >> 3;
  const int jlo = t & 7;
  float4 acc0 = make_float4(0.f, 0.f, 0.f, 0.f);
  float4 acc1 = acc0, acc2 = acc0, acc3 = acc0;

#define PAIR(ACC, RP, LP, WA, WB)                                             \
  {                                                                           \
    __half2 xp = __hmul2(RP, LP);          /* v_pk_mul_f16 */                 \
    float x0 = __low2float(xp), x1 = __high2float(xp);                        \
    float u0 = tanh_pre(x0), u1 = tanh_pre(x1);                               \
    ACC.x = fmaf(u0, WA.x, fmaf(u1, WB.x, ACC.x));                            \
    ACC.y = fmaf(u0, WA.y, fmaf(u1, WB.y, ACC.y));                            \
    ACC.z = fmaf(u0, WA.z, fmaf(u1, WB.z, ACC.z));                            \
    ACC.w = fmaf(u0, WA.w, fmaf(u1, WB.w, ACC.w));                            \
  }
#define DO_JJ(ACC, JJ)                                                        \
  {                                                                           \
    H8 l8 = *(const H8*)&ll[(JJ)][h];                                         \
    PAIR(ACC, r8.p[0], l8.p[0], w0, w1)                                       \
    PAIR(ACC, r8.p[1], l8.p[1], w2, w3)                                       \
    PAIR(ACC, r8.p[2], l8.p[2], w4, w5)                                       \
    PAIR(ACC, r8.p[3], l8.p[3], w6, w7)                                       \
  }

  for (int h = 0; h < HDIM; h += 8) {
    H8 r8 = *(const H8*)&rl[ii][h];
    float4 w0 = wl[h + 0], w1 = wl[h + 1], w2 = wl[h + 2], w3 = wl[h + 3];
    float4 w4 = wl[h + 4], w5 = wl[h + 5], w6 = wl[h + 6], w7 = wl[h + 7];
    DO_JJ(acc0, jlo)
    DO_JJ(acc1, jlo + 8)
    DO_JJ(acc2, jlo + 16)
    DO_JJ(acc3, jlo + 24)
  }
#undef DO_JJ
#undef PAIR
  sl[ii][jlo]      = acc0;
  sl[ii][jlo + 8]  = acc1;
  sl[ii][jlo + 16] = acc2;
  sl[ii][jlo + 24] = acc3;
  __syncthreads();

  // phase C: y[i,j] = cb + s00(i-1,j-1)+s01(i-1,j)+s10(i,j-1)+s11(i,j); max
  float m = -INFINITY;
  const float cbv = cb[0];
  for (int p = t; p < 1024; p += 256) {
    int jj = p & 31, iy = p >> 5;
    int i = ib + iy, j = jb + jj;
    if (iy > 0 && jj > 0 && i < LDIM && j < LDIM) {
      float v = cbv + sl[iy - 1][jj - 1].x + sl[iy - 1][jj].y
                    + sl[iy][jj - 1].z + sl[iy][jj].w;
      m = fmaxf(m, v);
    }
  }
#pragma unroll
  for (int off = 32; off > 0; off >>= 1) m = fmaxf(m, __shfl_down(m, off, 64));
  if ((t & 63) == 0) wred[t >> 6] = m;
  __syncthreads();
  if (t == 0) {
    float mm = fmaxf(fmaxf(wred[0], wred[1]), fmaxf(wred[2], wred[3]));
    partial[((size_t)b * NT + blockIdx.y) * NT + blockIdx.x] = mm;
  }
}

// ---------------------------------------------------------------------------
// Kernel 3: reduce 17x17 partials per batch, sigmoid, write 4 outputs.
// ---------------------------------------------------------------------------
__global__ __launch_bounds__(64) void finalize(const float* __restrict__ partial,
                                               float* __restrict__ out) {
  const int b = blockIdx.x, t = threadIdx.x;
  float m = -INFINITY;
  for (int p = t; p < NT * NT; p += 64) m = fmaxf(m, partial[b * NT * NT + p]);
#pragma unroll
  for (int off = 32; off > 0; off >>= 1) m = fmaxf(m, __shfl_down(m, off, 64));
  if (t == 0) out[b] = 1.f / (1.f + expf(-m));
}

extern "C" void kernel_launch(void* const* d_in, const int* in_sizes, int n_in,
                              void* d_out, int out_size, void* d_ws, size_t ws_size,
                              hipStream_t stream) {
  const float* rec = (const float*)d_in[0];
  const float* lig = (const float*)d_in[1];
  const float* W1  = (const float*)d_in[2];
  const float* b1  = (const float*)d_in[3];
  const float* cw  = (const float*)d_in[4];   // (1,H,2,2) = float4 per h
  const float* cb  = (const float*)d_in[5];
  float* out = (float*)d_out;

  ushort_t* Wt    = (ushort_t*)d_ws;                    // 128x1024 f16 = 256 KB
  ushort_t* hid_h = Wt + (size_t)HDIM * EDIM;           // 4096x128 f16 = 1 MB
  float* partial  = (float*)(hid_h + (size_t)2 * BDIM * LDIM * HDIM);

  wcvt<<<dim3(64), 256, 0, stream>>>(W1, Wt);
  gemm_f16<<<dim3(2 * BDIM * LDIM / 16), 256, 0, stream>>>(rec, lig, Wt, b1, hid_h);
  bilinear_max<<<dim3(NT, NT, BDIM), 256, 0, stream>>>(hid_h, (const float4*)cw, cb, partial);
  finalize<<<dim3(BDIM), 64, 0, stream>>>(partial, out);
}

// Round 5
// 141.579 us; speedup vs baseline: 1.7436x; 1.0116x over previous
//
#include <hip/hip_runtime.h>
#include <hip/hip_fp16.h>
#include <math.h>

#define BDIM 4
#define LDIM 512
#define EDIM 1024
#define HDIM 128
#define TILE 31            // interior y-tile per block (s-grid is 32x32 with 1 halo)
#define NT   17            // 17*31 = 527 >= 512 tiles per spatial dim
#define K2   2.885390081777927f   // 2/ln(2): tanh(x) = 1 - 2/(exp2(K2*x)+1)
#define KC   64            // gemm K-chunk

typedef unsigned short ushort_t;
typedef __attribute__((ext_vector_type(8))) _Float16 half8;
typedef __attribute__((ext_vector_type(4))) float f32x4;

struct __align__(16) H8 { __half2 p[4]; };
struct __align__(8)  H4 { __half2 a, b; };

__device__ __forceinline__ float sum_h2(__half2 v) {
  return __low2float(v) + __high2float(v);
}

// ---------------------------------------------------------------------------
// Kernel 0: W1 (1024x128 f32, k-major) -> Wt (128x1024 f16, n-major).
// ---------------------------------------------------------------------------
__global__ __launch_bounds__(256) void wcvt(const float* __restrict__ W1,
                                            ushort_t* __restrict__ Wt) {
  const int g = (int)blockIdx.x * 256 + threadIdx.x;  // 0..16383
  const int n = g & 127, k8 = g >> 7;                 // k8: 0..127
  float v[8];
#pragma unroll
  for (int j = 0; j < 8; ++j) v[j] = W1[(size_t)(k8 * 8 + j) * HDIM + n];
  H8 o;
#pragma unroll
  for (int j = 0; j < 4; ++j) o.p[j] = __floats2half2_rn(v[2 * j], v[2 * j + 1]);
  *(H8*)&Wt[(size_t)n * EDIM + k8 * 8] = o;
}

// ---------------------------------------------------------------------------
// Kernel 1: hid = relu(emb @ W1 + b1) via f16 MFMA 16x16x32, f16 output
// (rec rows pre-scaled by K2). 256 blocks x 16 rows. Register double-buffer:
// chunk c+1 global loads issued before chunk-c MFMAs; the vmcnt wait lands at
// the post-MFMA ds_write, so load latency overlaps compute. Single LDS buffer,
// rows padded to 72 halves (144 B) -> 2-way (free) b128 frag reads.
// ---------------------------------------------------------------------------
__global__ __launch_bounds__(256) void gemm_f16(
    const float* __restrict__ rec, const float* __restrict__ lig,
    const ushort_t* __restrict__ Wt, const float* __restrict__ b1,
    ushort_t* __restrict__ hid) {
  __shared__ ushort_t Wl[128][72];   // 18 KB
  __shared__ ushort_t Al[16][72];    // 2.25 KB
  const int t = threadIdx.x;
  const int r0 = (int)blockIdx.x * 16;
  const float* abase = (r0 < BDIM * LDIM)
                           ? rec + (size_t)r0 * EDIM
                           : lig + (size_t)(r0 - BDIM * LDIM) * EDIM;
  // staging: W row t>>1, 32 halves at (t&1)*32; A row t>>4, 4 floats at (t&15)*4
  const int wr = t >> 1, wko = (t & 1) * 32;
  const int am = t >> 4, ak4 = (t & 15) * 4;
  const ushort_t* wsrc = Wt + (size_t)wr * EDIM + wko;
  const float* asrc = abase + (size_t)am * EDIM + ak4;
  // frags
  const int l = t & 63, wv = t >> 6;
  const int kg = (l >> 4) * 8, m = l & 15;
  const int n0 = wv * 32 + m, n1 = n0 + 16;

  f32x4 acc0 = {0.f, 0.f, 0.f, 0.f}, acc1 = {0.f, 0.f, 0.f, 0.f};
  H8 wv0, wv1, wv2, wv3;
  float4 av;

#define LOADC(K0)                                                             \
  wv0 = *(const H8*)(wsrc + (K0));                                            \
  wv1 = *(const H8*)(wsrc + (K0) + 8);                                        \
  wv2 = *(const H8*)(wsrc + (K0) + 16);                                       \
  wv3 = *(const H8*)(wsrc + (K0) + 24);                                       \
  av = *(const float4*)(asrc + (K0));
#define WRITEC()                                                              \
  *(H8*)&Wl[wr][wko] = wv0;                                                   \
  *(H8*)&Wl[wr][wko + 8] = wv1;                                               \
  *(H8*)&Wl[wr][wko + 16] = wv2;                                              \
  *(H8*)&Wl[wr][wko + 24] = wv3;                                              \
  {                                                                           \
    H4 ah;                                                                    \
    ah.a = __floats2half2_rn(av.x, av.y);                                     \
    ah.b = __floats2half2_rn(av.z, av.w);                                     \
    *(H4*)&Al[am][ak4] = ah;                                                  \
  }

  LOADC(0)
  WRITEC()
  __syncthreads();
  for (int c = 0; c < EDIM / KC; ++c) {
    if (c < EDIM / KC - 1) LOADC((c + 1) * KC)   // prefetch, waited at WRITEC
    half8 a0  = *(const half8*)&Al[m][kg];
    half8 a1  = *(const half8*)&Al[m][32 + kg];
    half8 b00 = *(const half8*)&Wl[n0][kg];
    half8 b01 = *(const half8*)&Wl[n0][32 + kg];
    half8 b10 = *(const half8*)&Wl[n1][kg];
    half8 b11 = *(const half8*)&Wl[n1][32 + kg];
    acc0 = __builtin_amdgcn_mfma_f32_16x16x32_f16(a0, b00, acc0, 0, 0, 0);
    acc1 = __builtin_amdgcn_mfma_f32_16x16x32_f16(a0, b10, acc1, 0, 0, 0);
    acc0 = __builtin_amdgcn_mfma_f32_16x16x32_f16(a1, b01, acc0, 0, 0, 0);
    acc1 = __builtin_amdgcn_mfma_f32_16x16x32_f16(a1, b11, acc1, 0, 0, 0);
    if (c < EDIM / KC - 1) {
      __syncthreads();   // all frag reads done before overwrite
      WRITEC()
      __syncthreads();   // writes visible
    }
  }
#undef LOADC
#undef WRITEC

  // C/D: col = lane&15, row = (lane>>4)*4 + reg  [m89-verified]
  const float scale = (r0 < BDIM * LDIM) ? K2 : 1.0f;
  const int rbase = r0 + ((l >> 4) << 2);
  const int col0 = (wv << 5) + m;
#pragma unroll
  for (int nt = 0; nt < 2; ++nt) {
    const int col = col0 + nt * 16;
    const float bias = b1[col];
    f32x4 a = nt ? acc1 : acc0;
#pragma unroll
    for (int r = 0; r < 4; ++r) {
      float v = fmaxf(a[r] + bias, 0.f) * scale;
      ((_Float16*)hid)[(size_t)(rbase + r) * HDIM + col] = (_Float16)v;
    }
  }
}

// ---------------------------------------------------------------------------
// Kernel 2: per 31x31 y-tile: s_k(p,q) = Wsum_k + sum_h (-2 w_k[h]) * g(p,q,h),
// g = rcp(1 + exp2(K2 * r_p[h] * l_q[h]))  (tanh folded through weights).
// f16 transcendentals on packed products; pk_fma f16 accumulation (even/odd
// split); f32 tap assembly. 4 blocks/CU.
// ---------------------------------------------------------------------------
__global__ __launch_bounds__(256, 4) void bilinear_max(
    const ushort_t* __restrict__ hid, const float4* __restrict__ cw4,
    const float* __restrict__ cb, float* __restrict__ partial) {
  __shared__ ushort_t rl[32][136];   // 272 B row stride
  __shared__ ushort_t ll[32][136];
  __shared__ __half whl[4][HDIM];    // -2*w_k[h] as f16, h-contiguous
  __shared__ float4 sl[32][33];
  __shared__ float wred[4];
  __shared__ float4 wpart[2];

  const int t = threadIdx.x;
  const int b = blockIdx.z;
  const int ib = (int)blockIdx.y * TILE - 1;
  const int jb = (int)blockIdx.x * TILE - 1;

  if (t < HDIM) {
    float4 w4 = cw4[t];
    whl[0][t] = __float2half(-2.f * w4.x);
    whl[1][t] = __float2half(-2.f * w4.y);
    whl[2][t] = __float2half(-2.f * w4.z);
    whl[3][t] = __float2half(-2.f * w4.w);
    float4 ws = w4;
#pragma unroll
    for (int off = 32; off > 0; off >>= 1) {
      ws.x += __shfl_down(ws.x, off, 64);
      ws.y += __shfl_down(ws.y, off, 64);
      ws.z += __shfl_down(ws.z, off, 64);
      ws.w += __shfl_down(ws.w, off, 64);
    }
    if ((t & 63) == 0) wpart[t >> 6] = ws;
  }
  H8 z;
  z.p[0] = z.p[1] = z.p[2] = z.p[3] = __floats2half2_rn(0.f, 0.f);
  for (int p = t; p < 1024; p += 256) {   // 64 rows x 16 b128 segments
    int r = p >> 4, seg = (p & 15) * 8;
    if (r < 32) {
      int i = ib + r;
      H8 v = z;
      if (i >= 0 && i < LDIM) v = *(const H8*)&hid[((size_t)(b * LDIM + i)) * HDIM + seg];
      *(H8*)&rl[r][seg] = v;
    } else {
      int j = jb + (r - 32);
      H8 v = z;
      if (j >= 0 && j < LDIM) v = *(const H8*)&hid[((size_t)((BDIM + b) * LDIM + j)) * HDIM + seg];
      *(H8*)&ll[r - 32][seg] = v;
    }
  }
  __syncthreads();
  float4 wp0 = wpart[0], wp1 = wpart[1];
  const float4 wsum = make_float4(wp0.x + wp1.x, wp0.y + wp1.y,
                                  wp0.z + wp1.z, wp0.w + wp1.w);

  // phase B: thread = one ii row x 4 jj cols (jlo, +8, +16, +24)
  const int ii = t >> 3;
  const int jlo = t & 7;
  const __half2 one2 = __float2half2_rn(1.0f);
  __half2 aE[4][4], aO[4][4];   // [jjgroup][k], even(i=0,1)/odd(i=2,3) octet halves
#pragma unroll
  for (int q = 0; q < 4; ++q)
#pragma unroll
    for (int k = 0; k < 4; ++k) {
      aE[q][k] = __float2half2_rn(0.f);
      aO[q][k] = __float2half2_rn(0.f);
    }

#define DO_JJ(Q, JJ)                                                          \
  {                                                                           \
    H8 l8 = *(const H8*)&ll[(JJ)][h];                                         \
    __half2 g0 = h2rcp(__hadd2(h2exp2(__hmul2(r8.p[0], l8.p[0])), one2));     \
    __half2 g1 = h2rcp(__hadd2(h2exp2(__hmul2(r8.p[1], l8.p[1])), one2));     \
    __half2 g2 = h2rcp(__hadd2(h2exp2(__hmul2(r8.p[2], l8.p[2])), one2));     \
    __half2 g3 = h2rcp(__hadd2(h2exp2(__hmul2(r8.p[3], l8.p[3])), one2));     \
    _Pragma("unroll")                                                         \
    for (int k = 0; k < 4; ++k) {                                             \
      aE[Q][k] = __hfma2(g0, wk[k].p[0], aE[Q][k]);                           \
      aE[Q][k] = __hfma2(g1, wk[k].p[1], aE[Q][k]);                           \
      aO[Q][k] = __hfma2(g2, wk[k].p[2], aO[Q][k]);                           \
      aO[Q][k] = __hfma2(g3, wk[k].p[3], aO[Q][k]);                           \
    }                                                                         \
  }

  for (int h = 0; h < HDIM; h += 8) {
    H8 r8 = *(const H8*)&rl[ii][h];
    H8 wk[4];
#pragma unroll
    for (int k = 0; k < 4; ++k) wk[k] = *(const H8*)&whl[k][h];
    DO_JJ(0, jlo)
    DO_JJ(1, jlo + 8)
    DO_JJ(2, jlo + 16)
    DO_JJ(3, jlo + 24)
  }
#undef DO_JJ

#pragma unroll
  for (int q = 0; q < 4; ++q) {
    float4 s;
    s.x = wsum.x + sum_h2(aE[q][0]) + sum_h2(aO[q][0]);
    s.y = wsum.y + sum_h2(aE[q][1]) + sum_h2(aO[q][1]);
    s.z = wsum.z + sum_h2(aE[q][2]) + sum_h2(aO[q][2]);
    s.w = wsum.w + sum_h2(aE[q][3]) + sum_h2(aO[q][3]);
    sl[ii][jlo + q * 8] = s;
  }
  __syncthreads();

  // phase C: y[i,j] = cb + s00(i-1,j-1)+s01(i-1,j)+s10(i,j-1)+s11(i,j); max
  float m = -INFINITY;
  const float cbv = cb[0];
  for (int p = t; p < 1024; p += 256) {
    int jj = p & 31, iy = p >> 5;
    int i = ib + iy, j = jb + jj;
    if (iy > 0 && jj > 0 && i < LDIM && j < LDIM) {
      float v = cbv + sl[iy - 1][jj - 1].x + sl[iy - 1][jj].y
                    + sl[iy][jj - 1].z + sl[iy][jj].w;
      m = fmaxf(m, v);
    }
  }
#pragma unroll
  for (int off = 32; off > 0; off >>= 1) m = fmaxf(m, __shfl_down(m, off, 64));
  if ((t & 63) == 0) wred[t >> 6] = m;
  __syncthreads();
  if (t == 0) {
    float mm = fmaxf(fmaxf(wred[0], wred[1]), fmaxf(wred[2], wred[3]));
    partial[((size_t)b * NT + blockIdx.y) * NT + blockIdx.x] = mm;
  }
}

// ---------------------------------------------------------------------------
// Kernel 3: reduce 17x17 partials per batch, sigmoid, write 4 outputs.
// ---------------------------------------------------------------------------
__global__ __launch_bounds__(64) void finalize(const float* __restrict__ partial,
                                               float* __restrict__ out) {
  const int b = blockIdx.x, t = threadIdx.x;
  float m = -INFINITY;
  for (int p = t; p < NT * NT; p += 64) m = fmaxf(m, partial[b * NT * NT + p]);
#pragma unroll
  for (int off = 32; off > 0; off >>= 1) m = fmaxf(m, __shfl_down(m, off, 64));
  if (t == 0) out[b] = 1.f / (1.f + expf(-m));
}

extern "C" void kernel_launch(void* const* d_in, const int* in_sizes, int n_in,
                              void* d_out, int out_size, void* d_ws, size_t ws_size,
                              hipStream_t stream) {
  const float* rec = (const float*)d_in[0];
  const float* lig = (const float*)d_in[1];
  const float* W1  = (const float*)d_in[2];
  const float* b1  = (const float*)d_in[3];
  const float* cw  = (const float*)d_in[4];   // (1,H,2,2) = float4 per h
  const float* cb  = (const float*)d_in[5];
  float* out = (float*)d_out;

  ushort_t* Wt    = (ushort_t*)d_ws;                    // 128x1024 f16 = 256 KB
  ushort_t* hid_h = Wt + (size_t)HDIM * EDIM;           // 4096x128 f16 = 1 MB
  float* partial  = (float*)(hid_h + (size_t)2 * BDIM * LDIM * HDIM);

  wcvt<<<dim3(64), 256, 0, stream>>>(W1, Wt);
  gemm_f16<<<dim3(2 * BDIM * LDIM / 16), 256, 0, stream>>>(rec, lig, Wt, b1, hid_h);
  bilinear_max<<<dim3(NT, NT, BDIM), 256, 0, stream>>>(hid_h, (const float4*)cw, cb, partial);
  finalize<<<dim3(BDIM), 64, 0, stream>>>(partial, out);
}